// Round 15
// baseline (1641.473 us; speedup 1.0000x reference)
//
#include <hip/hip_runtime.h>

#define BB 512
#define TT 200
#define VV 2048
#define EE 20
#define HH 100
#define G4 400   // 4*H
#define II 64
#define AA 32
#define NT 25    // 16-wide tiles over gate dim 400 (rows reordered r' = 4j+g)
#define NCHUNK 64

typedef _Float16 half8 __attribute__((ext_vector_type(8)));
typedef float    f32x4 __attribute__((ext_vector_type(4)));

// ---------------- workspace layout (4-byte units) ----------------
#define WS_BF_OFF    1024                        // W_emb B-frags: 65536 half
#define WS_WIHF_OFF  (WS_BF_OFF + 32768)         // W_ih' A-frags: 12800 half
#define WS_WHHF_OFF  (WS_WIHF_OFF + 6400)        // W_hh' A-frags: 51200 half
#define WS_BIASC_OFF (WS_WHHF_OFF + 25600)       // 400 f  (b_ih+b_hh, r' order)

// ---------------- Kernel 0: weight fragment packs (off kept, unused) ----------------
__global__ __launch_bounds__(512) void k0_prep(
    const int* __restrict__ lengths, const float* __restrict__ W_emb,
    const float* __restrict__ W_ih, const float* __restrict__ W_hh,
    const float* __restrict__ b_ih, const float* __restrict__ b_hh,
    int* __restrict__ off, _Float16* __restrict__ Bfrag,
    _Float16* __restrict__ Wihf, _Float16* __restrict__ Whhf,
    float* __restrict__ biasc)
{
    if (blockIdx.x == 0) {
        __shared__ int s[BB];
        int tid = threadIdx.x;
        s[tid] = lengths[tid];
        __syncthreads();
        for (int d = 1; d < BB; d <<= 1) {
            int v = (tid >= d) ? s[tid - d] : 0;
            __syncthreads();
            if (tid >= d) s[tid] += v;
            __syncthreads();
        }
        off[tid + 1] = s[tid];
        if (tid == 0) off[0] = 0;
        return;
    }
    int F = (blockIdx.x - 1) * 512 + threadIdx.x;
    if (F < 65536) {                       // W_emb B-frags
        int e = F & 7, l = (F >> 3) & 63, nn = (F >> 9) & 1, c = F >> 10;
        int k = c * 32 + (l >> 4) * 8 + e;
        int col = nn * 16 + (l & 15);
        float v = (col < EE) ? W_emb[(size_t)col * VV + k] : 0.f;
        Bfrag[F] = (_Float16)v;
        return;
    }
    F -= 65536;
    if (F < 12800) {                       // W_ih' A-frags: [m][lane][8]
        int e = F & 7, l = (F >> 3) & 63, nt = F >> 9;
        int rp = nt * 16 + (l & 15);       // r' = 4j+g
        int j = rp >> 2, g = rp & 3;
        int k = 8 * (l >> 4) + e;          // 0..31
        float v = (k < EE) ? W_ih[(size_t)(g * HH + j) * EE + k] : 0.f;
        Wihf[F] = (_Float16)v;
        return;
    }
    F -= 12800;
    if (F < 51200) {                       // W_hh' A-frags: [m][c][lane][8]
        int e = F & 7, l = (F >> 3) & 63, c = (F >> 9) & 3, m = F >> 11;
        int rp = m * 16 + (l & 15);
        int j = rp >> 2, g = rp & 3;
        int k = 32 * c + 8 * (l >> 4) + e; // 0..127
        float v = (k < HH) ? W_hh[(size_t)(g * HH + j) * HH + k] : 0.f;
        Whhf[F] = (_Float16)v;
        return;
    }
    F -= 51200;
    if (F < 400) {                         // biasc in r' order
        int j = F >> 2, g = F & 3;
        biasc[F] = b_ih[g * HH + j] + b_hh[g * HH + j];
    }
}

// ---------------- Kernel 2: MFMA LSTM with fused in-loop embedding GEMM ----------------
__device__ __forceinline__ float fast_sig(float x) { return 1.f / (1.f + __expf(-x)); }
__device__ __forceinline__ float fast_tanh(float x) { return 2.f * fast_sig(2.f * x) - 1.f; }

#define SACC2(C, J) sacc##C##_##J
#define SACC(C, J)  SACC2(C, J)

#define STEP(T_, CUR_)  do {                                                                  \
    const int sb_ = ((T_) >> 4) & 1;                                                          \
    const int p_  = (T_) & 15;                                                                \
    const int nw_ = ((T_) >> 4) + 1;                                                          \
    const bool stg_ = (16 * nw_) < tmax;                                                      \
    /* scan LDS reads issue first */                                                          \
    uint4 xb_  = *reinterpret_cast<const uint4*>(&estage[sb_][p_][n][rg * 8]);                \
    uint4 rb0_ = *reinterpret_cast<const uint4*>(&bfrag[CUR_][0][lane][0]);                   \
    uint4 rb1_ = *reinterpret_cast<const uint4*>(&bfrag[CUR_][1][lane][0]);                   \
    uint4 rb2_ = *reinterpret_cast<const uint4*>(&bfrag[CUR_][2][lane][0]);                   \
    uint4 rb3_ = *reinterpret_cast<const uint4*>(&bfrag[CUR_][3][lane][0]);                   \
    /* staging A-loads issue early; consumed at step bottom (latency hidden by scan) */       \
    float4 sa_[8], sb4_[8];                                                                   \
    if (stg_) {                                                                               \
        int ts_ = 16 * nw_ + 2 * w + (CUR_);                                                  \
        ts_ = (ts_ < lm1_l) ? ts_ : lm1_l;                                                    \
        const float* ap_ = abase + (size_t)ts_ * VV + (p_ >> 1) * 256;                        \
        _Pragma("unroll")                                                                     \
        for (int q_ = 0; q_ < 8; ++q_) {                                                      \
            sa_[q_]  = *reinterpret_cast<const float4*>(ap_ + q_ * 32);                       \
            sb4_[q_] = *reinterpret_cast<const float4*>(ap_ + q_ * 32 + 4);                   \
        }                                                                                     \
    }                                                                                         \
    /* scan core (unchanged from R14) */                                                      \
    _Pragma("unroll")                                                                         \
    for (int it = 0; it < 4; ++it) if (it < ntile) {                                          \
        f32x4 acc = biasf[it];                                                                \
        acc = __builtin_amdgcn_mfma_f32_16x16x32_f16(wif[it], __builtin_bit_cast(half8, xb_), acc, 0, 0, 0); \
        acc = __builtin_amdgcn_mfma_f32_16x16x32_f16(af[it][0], __builtin_bit_cast(half8, rb0_), acc, 0, 0, 0); \
        acc = __builtin_amdgcn_mfma_f32_16x16x32_f16(af[it][1], __builtin_bit_cast(half8, rb1_), acc, 0, 0, 0); \
        acc = __builtin_amdgcn_mfma_f32_16x16x32_f16(af[it][2], __builtin_bit_cast(half8, rb2_), acc, 0, 0, 0); \
        acc = __builtin_amdgcn_mfma_f32_16x16x32_f16(af[it][3], __builtin_bit_cast(half8, rb3_), acc, 0, 0, 0); \
        float gi = fast_sig(acc[0]);                                                          \
        float gf = fast_sig(acc[1]);                                                          \
        float gg = fast_tanh(acc[2]);                                                         \
        float go = fast_sig(acc[3]);                                                          \
        cst[it] = gf * cst[it] + gi * gg;                                                     \
        float hv = go * fast_tanh(cst[it]);                                                   \
        int j_ = jidx[it];                                                                    \
        if ((T_) == len_n - 1) hfin[n][j_] = hv;                                              \
        int kk_ = j_ & 31;                                                                    \
        _Float16* hp_ = (_Float16*)&bfrag[(CUR_) ^ 1][j_ >> 5][((kk_ >> 3) << 4) | n][(kk_ & 7) >> 1]; \
        hp_[kk_ & 1] = (_Float16)hv;                                                          \
    }                                                                                         \
    /* staging MFMAs (A loads long in flight by now) */                                       \
    if (stg_) {                                                                               \
        _Pragma("unroll")                                                                     \
        for (int q_ = 0; q_ < 8; ++q_) {                                                      \
            half8 bf0_ = bptr[(((p_ >> 1) * 8 + q_) * 2 + 0) * 64];                           \
            half8 bf1_ = bptr[(((p_ >> 1) * 8 + q_) * 2 + 1) * 64];                           \
            half8 av_;                                                                        \
            av_[0] = (_Float16)sa_[q_].x;  av_[1] = (_Float16)sa_[q_].y;                      \
            av_[2] = (_Float16)sa_[q_].z;  av_[3] = (_Float16)sa_[q_].w;                      \
            av_[4] = (_Float16)sb4_[q_].x; av_[5] = (_Float16)sb4_[q_].y;                     \
            av_[6] = (_Float16)sb4_[q_].z; av_[7] = (_Float16)sb4_[q_].w;                     \
            SACC(CUR_,0) = __builtin_amdgcn_mfma_f32_16x16x32_f16(av_, bf0_, SACC(CUR_,0), 0, 0, 0); \
            SACC(CUR_,1) = __builtin_amdgcn_mfma_f32_16x16x32_f16(av_, bf1_, SACC(CUR_,1), 0, 0, 0); \
        }                                                                                     \
        if (p_ == 15) {                                                                       \
            _Float16* eb_ = &estage[sb_ ^ 1][0][0][0];                                        \
            _Pragma("unroll")                                                                 \
            for (int rr_ = 0; rr_ < 4; ++rr_) {                                               \
                int nn_ = 4 * rg + rr_;                                                       \
                eb_[((2 * w) * 16 + nn_) * 40 + n]     = (_Float16)(sacc0_0[rr_] + bias0_l);  \
                eb_[((2 * w + 1) * 16 + nn_) * 40 + n] = (_Float16)(sacc1_0[rr_] + bias0_l);  \
                if (n < 4) {                                                                  \
                    eb_[((2 * w) * 16 + nn_) * 40 + 16 + n]     = (_Float16)(sacc0_1[rr_] + bias1_l); \
                    eb_[((2 * w + 1) * 16 + nn_) * 40 + 16 + n] = (_Float16)(sacc1_1[rr_] + bias1_l); \
                }                                                                             \
            }                                                                                 \
            sacc0_0 = zf4; sacc0_1 = zf4; sacc1_0 = zf4; sacc1_1 = zf4;                       \
        }                                                                                     \
    }                                                                                         \
    __syncthreads();                                                                          \
} while (0)

__global__ __launch_bounds__(512, 1) void k2_lstm(
    const float* __restrict__ batch, const int* __restrict__ lengths,
    const _Float16* __restrict__ Bfrag, const _Float16* __restrict__ Whhf,
    const _Float16* __restrict__ Wihf, const float* __restrict__ biasc,
    const float* __restrict__ b_emb,
    const float* __restrict__ W1, const float* __restrict__ b1,
    const float* __restrict__ W2, const float* __restrict__ b2,
    const float* __restrict__ h0, const float* __restrict__ c0,
    float* __restrict__ out)
{
    __shared__ __align__(16) unsigned int bfrag[2][4][64][4];   // 8 KB h B-frags
    __shared__ __align__(16) _Float16 estage[2][16][16][40];    // 40 KB emb stage
    __shared__ float hfin[16][HH];
    __shared__ float inter[16][II];
    __shared__ int len_s[16];

    const int tid  = threadIdx.x;
    const int lane = tid & 63;
    const int w    = tid >> 6;
    const int b0   = blockIdx.x * 16;
    const int n    = lane & 15, rg = lane >> 4;
    const f32x4 zf4 = {0.f, 0.f, 0.f, 0.f};

    if (tid < 16) len_s[tid] = lengths[b0 + tid];
    for (int i = tid; i < 2 * 4 * 64 * 4; i += 512) (&bfrag[0][0][0][0])[i] = 0u;
    for (int i = tid; i < 2 * 16 * 16 * 40 / 2; i += 512)
        reinterpret_cast<unsigned int*>(&estage[0][0][0][0])[i] = 0u;
    __syncthreads();

    int tmax = 0;
#pragma unroll
    for (int k = 0; k < 16; ++k) tmax = max(tmax, len_s[k]);

    const int ntile = (w == 7) ? 4 : 3;
    const int m0    = (w < 7) ? 3 * w : 21;
    const int len_n = len_s[n];
    const int lm1_l = len_s[n] - 1;

    // staging constants
    const float* abase = batch + (size_t)(b0 + n) * TT * VV + rg * 8;
    const half8* bptr  = reinterpret_cast<const half8*>(Bfrag) + lane;
    const float bias0_l = b_emb[n];
    const float bias1_l = (n < 4) ? b_emb[16 + n] : 0.f;

    // scan setup (unchanged)
    half8 af[4][4];
    half8 wif[4];
    f32x4 biasf[4];
    float cst[4];
    int   jidx[4];
#pragma unroll
    for (int it = 0; it < 4; ++it) if (it < ntile) {
        const int m = m0 + it;
#pragma unroll
        for (int c = 0; c < 4; ++c)
            af[it][c] = reinterpret_cast<const half8*>(Whhf)[((m * 4 + c) * 64) + lane];
        wif[it]   = reinterpret_cast<const half8*>(Wihf)[m * 64 + lane];
        biasf[it] = *reinterpret_cast<const f32x4*>(biasc + 16 * m + 4 * rg);
        const int j = 4 * m + rg;
        jidx[it] = j;
        cst[it] = c0[(size_t)(b0 + n) * HH + j];
        float hv = h0[(size_t)(b0 + n) * HH + j];
        int kk = j & 31;
        _Float16* hp = (_Float16*)&bfrag[0][j >> 5][((kk >> 3) << 4) | n][(kk & 7) >> 1];
        hp[kk & 1] = (_Float16)hv;
    }

    // prologue: compute estage chunk 0 (wave w -> time rows 2w, 2w+1)
    {
        int ts0 = 2 * w;     if (ts0 > lm1_l) ts0 = lm1_l;
        int ts1 = 2 * w + 1; if (ts1 > lm1_l) ts1 = lm1_l;
        const float* ap0 = abase + (size_t)ts0 * VV;
        const float* ap1 = abase + (size_t)ts1 * VV;
        f32x4 c00 = zf4, c01 = zf4, c10 = zf4, c11 = zf4;
#pragma unroll 4
        for (int kc = 0; kc < 64; ++kc) {
            float4 x0 = *reinterpret_cast<const float4*>(ap0 + kc * 32);
            float4 x1 = *reinterpret_cast<const float4*>(ap0 + kc * 32 + 4);
            float4 y0 = *reinterpret_cast<const float4*>(ap1 + kc * 32);
            float4 y1 = *reinterpret_cast<const float4*>(ap1 + kc * 32 + 4);
            half8 bf0 = bptr[(kc * 2 + 0) * 64];
            half8 bf1 = bptr[(kc * 2 + 1) * 64];
            half8 av0, av1;
            av0[0] = (_Float16)x0.x; av0[1] = (_Float16)x0.y;
            av0[2] = (_Float16)x0.z; av0[3] = (_Float16)x0.w;
            av0[4] = (_Float16)x1.x; av0[5] = (_Float16)x1.y;
            av0[6] = (_Float16)x1.z; av0[7] = (_Float16)x1.w;
            av1[0] = (_Float16)y0.x; av1[1] = (_Float16)y0.y;
            av1[2] = (_Float16)y0.z; av1[3] = (_Float16)y0.w;
            av1[4] = (_Float16)y1.x; av1[5] = (_Float16)y1.y;
            av1[6] = (_Float16)y1.z; av1[7] = (_Float16)y1.w;
            c00 = __builtin_amdgcn_mfma_f32_16x16x32_f16(av0, bf0, c00, 0, 0, 0);
            c01 = __builtin_amdgcn_mfma_f32_16x16x32_f16(av0, bf1, c01, 0, 0, 0);
            c10 = __builtin_amdgcn_mfma_f32_16x16x32_f16(av1, bf0, c10, 0, 0, 0);
            c11 = __builtin_amdgcn_mfma_f32_16x16x32_f16(av1, bf1, c11, 0, 0, 0);
        }
#pragma unroll
        for (int rr = 0; rr < 4; ++rr) {
            int nn_ = 4 * rg + rr;
            estage[0][2 * w][nn_][n]     = (_Float16)(c00[rr] + bias0_l);
            estage[0][2 * w + 1][nn_][n] = (_Float16)(c10[rr] + bias0_l);
            if (n < 4) {
                estage[0][2 * w][nn_][16 + n]     = (_Float16)(c01[rr] + bias1_l);
                estage[0][2 * w + 1][nn_][16 + n] = (_Float16)(c11[rr] + bias1_l);
            }
        }
    }
    f32x4 sacc0_0 = zf4, sacc0_1 = zf4, sacc1_0 = zf4, sacc1_1 = zf4;
    __syncthreads();

    for (int t = 0; t < tmax; t += 2) {
        STEP(t, 0);
        if (t + 1 < tmax) STEP(t + 1, 1);
    }
    __syncthreads();

    // fused MLP over the 16 batches
    for (int o = tid; o < 16 * II; o += 512) {
        int nn = o >> 6, i = o & 63;
        float a = b1[i];
        const float* w1r = W1 + i * HH;
        const float* hr  = &hfin[nn][0];
#pragma unroll
        for (int k = 0; k < HH; k += 4) {
            a += w1r[k] * hr[k] + w1r[k + 1] * hr[k + 1]
               + w1r[k + 2] * hr[k + 2] + w1r[k + 3] * hr[k + 3];
        }
        inter[nn][i] = fmaxf(a, 0.f);
    }
    __syncthreads();
    for (int o = tid; o < 16 * AA; o += 512) {
        int nn = o >> 5, ai = o & 31;
        float a = b2[ai];
        const float* w2r = W2 + ai * II;
#pragma unroll
        for (int k = 0; k < II; ++k) a += w2r[k] * inter[nn][k];
        out[(size_t)(b0 + nn) * AA + ai] = a;
    }
}

extern "C" void kernel_launch(void* const* d_in, const int* in_sizes, int n_in,
                              void* d_out, int out_size, void* d_ws, size_t ws_size,
                              hipStream_t stream) {
    const float* batch  = (const float*)d_in[0];
    const int*   lengths= (const int*)  d_in[1];
    const float* W_emb  = (const float*)d_in[2];
    const float* b_emb  = (const float*)d_in[3];
    const float* W_ih   = (const float*)d_in[4];
    const float* W_hh   = (const float*)d_in[5];
    const float* b_ih   = (const float*)d_in[6];
    const float* b_hh   = (const float*)d_in[7];
    const float* W1     = (const float*)d_in[8];
    const float* b1     = (const float*)d_in[9];
    const float* W2     = (const float*)d_in[10];
    const float* b2     = (const float*)d_in[11];
    const float* h0     = (const float*)d_in[12];
    const float* c0     = (const float*)d_in[13];
    float* out = (float*)d_out;

    int*       off   = (int*)d_ws;
    float*     wsf   = (float*)d_ws;
    _Float16*  Bfrag = (_Float16*)(wsf + WS_BF_OFF);
    _Float16*  Wihf  = (_Float16*)(wsf + WS_WIHF_OFF);
    _Float16*  Whhf  = (_Float16*)(wsf + WS_WHHF_OFF);
    float*     biasc = wsf + WS_BIASC_OFF;

    k0_prep<<<255, 512, 0, stream>>>(lengths, W_emb, W_ih, W_hh, b_ih, b_hh,
                                     off, Bfrag, Wihf, Whhf, biasc);
    k2_lstm<<<BB / 16, 512, 0, stream>>>(batch, lengths, Bfrag, Whhf, Wihf, biasc, b_emb,
                                         W1, b1, W2, b2, h0, c0, out);
}